// Round 1
// baseline (207.682 us; speedup 1.0000x reference)
//
#include <hip/hip_runtime.h>

namespace {
constexpr int kB = 8;
constexpr int kL = 4096;
constexpr int kD = 768;
constexpr int kW = 12;          // ATTN_WIDTH
constexpr int kHalo = kW - 1;   // 11 preceding rows needed
constexpr int kT = 32;          // rows per block (kL % kT == 0)
constexpr int kThreads = 192;   // 3 waves; 192 * 4 == kD
constexpr float kEps = 1e-7f;
constexpr int kChunks = kL / kT;
}

// Phase-2 inner loop. GUARD=true only for the first chunk of each batch
// (rows j < 0 must be skipped); all other chunks take the branch-free path.
template <bool GUARD>
__device__ __forceinline__ void phase2_loop(const float* __restrict__ xb,
                                            float* __restrict__ ob,
                                            const float* __restrict__ s_uf,
                                            const float* __restrict__ s_scale,
                                            int i0, int c0, float4& acc) {
#pragma unroll 4
  for (int t = 0; t < kT; ++t) {
    const int i = i0 + t;
    const float4 xv = *(const float4*)(xb + (size_t)i * kD + c0);
    const float ui = s_uf[t + kHalo];
    acc.x += ui * xv.x; acc.y += ui * xv.y;
    acc.z += ui * xv.z; acc.w += ui * xv.w;
    const float sc = s_scale[t];
    float4 o;
    o.x = sc * acc.x; o.y = sc * acc.y;
    o.z = sc * acc.z; o.w = sc * acc.w;
    *(float4*)(ob + (size_t)i * kD + c0) = o;
    const int j = i - kHalo;  // row leaving the window before next i
    if (!GUARD || j >= 0) {
      const float4 xo = *(const float4*)(xb + (size_t)j * kD + c0);
      const float uo = s_uf[t];
      acc.x -= uo * xo.x; acc.y -= uo * xo.y;
      acc.z -= uo * xo.z; acc.w -= uo * xo.w;
    }
  }
}

__global__ __launch_bounds__(kThreads) void SelfAttention_banded_kernel(
    const float* __restrict__ x, const float* __restrict__ Wa,
    float* __restrict__ out) {
  __shared__ double s_u[kT + kHalo];    // u for rows [i0-11, i0+kT), fp64
  __shared__ float s_uf[kT + kHalo];    // fp32 copy for phase 2
  __shared__ float s_scale[kT];         // u_i / (u_i*wsum_i + eps)

  const int blk = blockIdx.x;
  const int b = blk / kChunks;
  const int i0 = (blk % kChunks) * kT;
  const float* xb = x + (size_t)b * kL * kD;
  float* ob = out + (size_t)b * kL * kD;

  const int tid = threadIdx.x;
  const int lane = tid & 63;
  const int wv = tid >> 6;  // 0..2

  // Each lane owns 12 contiguous columns of Wa (64*12 = 768).
  float w[12];
#pragma unroll
  for (int c = 0; c < 12; ++c) w[c] = Wa[12 * lane + c];

  // ---- Phase 1: u (fp64) for rows [i0-11, i0+kT); one row per wave. ----
  for (int r_loc = wv; r_loc < kT + kHalo; r_loc += 3) {
    const int r = i0 - kHalo + r_loc;   // wave-uniform
    double partial = 0.0;
    if (r >= 0) {
      const float* xr = xb + (size_t)r * kD + 12 * lane;
#pragma unroll
      for (int c = 0; c < 12; ++c)
        partial += (double)xr[c] * (double)w[c];
    }
#pragma unroll
    for (int s = 32; s >= 1; s >>= 1)
      partial += __shfl_xor(partial, s, 64);
    if (lane == 0) {
      s_u[r_loc] = partial;
      s_uf[r_loc] = (float)partial;
    }
  }
  __syncthreads();

  // ---- wsum / denom / scale in fp64 (denom can be ~1e-5; fp32 here
  // would inject ~2%-of-absmax output error at near-singular rows). ----
  if (tid < kT) {
    const double u = s_u[tid + kHalo];
    double wsum = 0.0;
#pragma unroll
    for (int k = 0; k < kW; ++k) wsum += s_u[tid + k];
    const double denom = u * wsum + (double)kEps;
    s_scale[tid] = (float)(u / denom);
  }
  __syncthreads();

  // ---- Phase 2: sliding-window accumulator, 4 cols per thread. ----
  const int c0 = 4 * tid;
  float4 acc = make_float4(0.f, 0.f, 0.f, 0.f);
  if (i0 == 0) {
    // window is clipped at the sequence start; nothing to pre-accumulate
  } else {
#pragma unroll
    for (int k = 0; k < kHalo; ++k) {
      const int j = i0 - kHalo + k;
      const float4 xv = *(const float4*)(xb + (size_t)j * kD + c0);
      const float uj = s_uf[k];
      acc.x += uj * xv.x; acc.y += uj * xv.y;
      acc.z += uj * xv.z; acc.w += uj * xv.w;
    }
  }

  if (i0 >= kHalo) {
    phase2_loop<false>(xb, ob, s_uf, s_scale, i0, c0, acc);
  } else {
    phase2_loop<true>(xb, ob, s_uf, s_scale, i0, c0, acc);
  }
}

extern "C" void kernel_launch(void* const* d_in, const int* in_sizes, int n_in,
                              void* d_out, int out_size, void* d_ws, size_t ws_size,
                              hipStream_t stream) {
  const float* x = (const float*)d_in[0];
  const float* Wa = (const float*)d_in[1];
  float* out = (float*)d_out;
  const int grid = kB * kChunks;  // 8 * 128 = 1024 blocks
  SelfAttention_banded_kernel<<<grid, kThreads, 0, stream>>>(x, Wa, out);
}

// Round 3
// 200.250 us; speedup vs baseline: 1.0371x; 1.0371x over previous
//
#include <hip/hip_runtime.h>

namespace {
constexpr int kB = 8;
constexpr int kL = 4096;
constexpr int kD = 768;
constexpr int kW = 12;            // ATTN_WIDTH
constexpr int kHalo = kW - 1;     // 11 preceding rows
constexpr int kT = 32;            // rows per block (multiple of 16 -> ring slot = row&15)
constexpr int kRows = kT + kHalo; // 43 rows touched per block
constexpr int kThreads = 192;     // 3 waves; 192*4 == kD
constexpr float kEps = 1e-7f;
constexpr int kChunks = kL / kT;  // 128
constexpr int kRing = 16;         // ring >= kW, power of 2
}

// Native clang vector type: layout-identical to float4, but accepted by
// __builtin_nontemporal_store (HIP_vector_type is a struct and is rejected).
typedef float vfloat4 __attribute__((ext_vector_type(4)));

__global__ __launch_bounds__(kThreads, 3) void SelfAttention_banded_kernel(
    const float* __restrict__ x, const float* __restrict__ Wa,
    float* __restrict__ out) {
  __shared__ double s_part[kRows][3];  // per-wave fp64 partials of u
  __shared__ double s_u[kRows];        // u, fp64
  __shared__ float s_uf[kRows];        // u, fp32 (phase-2 dot)
  __shared__ float s_scale[kT];        // u_i / (u_i*wsum_i + eps)

  const int blk = blockIdx.x;
  const int b = blk / kChunks;
  const int i0 = (blk % kChunks) * kT;  // i0 % 16 == 0
  const float* xb = x + (size_t)b * kL * kD;
  float* ob = out + (size_t)b * kL * kD;

  const int tid = threadIdx.x;
  const int lane = tid & 63;
  const int wv = tid >> 6;   // 0..2
  const int c0 = 4 * tid;    // this thread's 4 columns (phase 1 AND phase 2)

  const vfloat4 w4 = *(const vfloat4*)(Wa + c0);

  // ---- Phase 1: u for rows [i0-11, i0+kT), coalesced dwordx4 loads. ----
  // 43 independent loads per thread -> deep memory pipelining. fp64 math:
  // denom = u*wsum + eps cancels to ~5e-5 at the worst row; u must be
  // accurate to ~1e-9 absolute or the output error blows the threshold.
#pragma unroll 4
  for (int r = 0; r < kRows; ++r) {
    const int row = i0 - kHalo + r;  // block-uniform guard (only chunk 0 diverges)
    double p = 0.0;
    if (row >= 0) {
      const vfloat4 xv = *(const vfloat4*)(xb + (size_t)row * kD + c0);
      p = (double)xv.x * (double)w4.x + (double)xv.y * (double)w4.y +
          (double)xv.z * (double)w4.z + (double)xv.w * (double)w4.w;
    }
#pragma unroll
    for (int s = 32; s >= 1; s >>= 1) p += __shfl_xor(p, s, 64);
    if (lane == 0) s_part[r][wv] = p;
  }
  __syncthreads();

  if (tid < kRows) {
    const double u = s_part[tid][0] + s_part[tid][1] + s_part[tid][2];
    s_u[tid] = u;
    s_uf[tid] = (float)u;
  }
  __syncthreads();

  if (tid < kT) {
    const double u = s_u[tid + kHalo];
    double wsum = 0.0;
#pragma unroll
    for (int k = 0; k < kW; ++k) wsum += s_u[tid + k];
    s_scale[tid] = (float)(u / (u * wsum + (double)kEps));
  }
  __syncthreads();

  // u -> registers (static indices below keep this in VGPRs, no LDS in loop)
  float uf[kRows];
#pragma unroll
  for (int r = 0; r < kRows; ++r) uf[r] = s_uf[r];

  // ---- Phase 2: 16-slot float4 register ring, one load + one store/row. ----
  vfloat4 ring[kRing];
  // prefill halo rows i0-11 .. i0-1 ; slot = row & 15 = (k+5)&15 (i0%16==0)
#pragma unroll
  for (int k = 0; k < kHalo; ++k) {
    const int row = i0 - kHalo + k;
    vfloat4 v = {0.f, 0.f, 0.f, 0.f};
    if (row >= 0) v = *(const vfloat4*)(xb + (size_t)row * kD + c0);
    ring[(k + kRing - kHalo) & (kRing - 1)] = v;
  }

#pragma unroll
  for (int t = 0; t < kT; ++t) {
    const int i = i0 + t;
    ring[t & (kRing - 1)] = *(const vfloat4*)(xb + (size_t)i * kD + c0);
    vfloat4 acc = {0.f, 0.f, 0.f, 0.f};
#pragma unroll
    for (int j = 0; j < kW; ++j) {
      const float u = uf[t + kHalo - j];             // static index
      const vfloat4 xv = ring[(t - j) & (kRing - 1)]; // static index
      acc.x += u * xv.x; acc.y += u * xv.y;
      acc.z += u * xv.z; acc.w += u * xv.w;
    }
    const float sc = s_scale[t];
    vfloat4 o;
    o.x = sc * acc.x; o.y = sc * acc.y;
    o.z = sc * acc.z; o.w = sc * acc.w;
    // output is never re-read: non-temporal keeps x tiles resident in L2
    __builtin_nontemporal_store(o, (vfloat4*)(ob + (size_t)i * kD + c0));
  }
}

extern "C" void kernel_launch(void* const* d_in, const int* in_sizes, int n_in,
                              void* d_out, int out_size, void* d_ws, size_t ws_size,
                              hipStream_t stream) {
  const float* x = (const float*)d_in[0];
  const float* Wa = (const float*)d_in[1];
  float* out = (float*)d_out;
  const int grid = kB * kChunks;  // 1024 blocks, 4/CU, 12 waves/CU
  SelfAttention_banded_kernel<<<grid, kThreads, 0, stream>>>(x, Wa, out);
}

// Round 4
// 198.868 us; speedup vs baseline: 1.0443x; 1.0070x over previous
//
#include <hip/hip_runtime.h>

// Native clang vector: layout-identical to float4, accepted by nontemporal builtins.
typedef float vfloat4 __attribute__((ext_vector_type(4)));

namespace {
constexpr int kB = 8;
constexpr int kL = 4096;
constexpr int kD = 768;
constexpr int kW = 12;           // ATTN_WIDTH
constexpr int kHalo = kW - 1;    // 11
constexpr float kEps = 1e-7f;

// K1: u = x @ Wa
constexpr int kRowsPerBlockU = 16;             // 4 waves x 4 rows
constexpr int kGridU = kB * kL / kRowsPerBlockU; // 2048

// K2: banded v
constexpr int kT2 = 16;                        // rows per block
constexpr int kRows2 = kT2 + kHalo;            // 27
constexpr int kThreads2 = 192;                 // 192*4 == kD
constexpr int kChunks2 = kL / kT2;             // 256
constexpr int kGridV = kB * kChunks2;          // 2048 -> 8 blocks/CU
}

// ---------------- K1: u[b,l] = sum_d x[b,l,d] * Wa[d]  (fp64 accum) -------
// Pure streaming matvec: 12 independent dwordx4 loads per wave, no barriers.
// fp64 is mandatory: denom = u*wsum+eps cancels to ~7e-5 at the worst row;
// fp32-level error in u would amplify past the output threshold.
__global__ __launch_bounds__(256, 4) void compute_u_kernel(
    const float* __restrict__ x, const float* __restrict__ Wa,
    double* __restrict__ u) {
  const int lane = threadIdx.x & 63;
  const int wv = threadIdx.x >> 6;  // 0..3
  const int rg0 = blockIdx.x * kRowsPerBlockU + wv * 4;  // 4 rows per wave

  vfloat4 w[3];
#pragma unroll
  for (int k = 0; k < 3; ++k)
    w[k] = *(const vfloat4*)(Wa + 4 * lane + 256 * k);

  // Issue all 12 loads before any math: deep memory pipeline.
  vfloat4 xv[4][3];
#pragma unroll
  for (int q = 0; q < 4; ++q)
#pragma unroll
    for (int k = 0; k < 3; ++k)
      xv[q][k] = *(const vfloat4*)(x + (size_t)(rg0 + q) * kD + 4 * lane + 256 * k);

  double acc[4];
#pragma unroll
  for (int q = 0; q < 4; ++q) {
    double p = 0.0;
#pragma unroll
    for (int k = 0; k < 3; ++k) {
      p += (double)xv[q][k].x * (double)w[k].x + (double)xv[q][k].y * (double)w[k].y +
           (double)xv[q][k].z * (double)w[k].z + (double)xv[q][k].w * (double)w[k].w;
    }
    acc[q] = p;
  }
#pragma unroll
  for (int q = 0; q < 4; ++q) {
#pragma unroll
    for (int s = 32; s >= 1; s >>= 1) acc[q] += __shfl_xor(acc[q], s, 64);
  }
  if (lane == 0) {
#pragma unroll
    for (int q = 0; q < 4; ++q) u[rg0 + q] = acc[q];
  }
}

// ---------------- K2: v_i = scale_i * sum_{j=0..11} u_{i-j} x_{i-j} -------
__global__ __launch_bounds__(kThreads2, 3) void banded_v_kernel(
    const float* __restrict__ x, const double* __restrict__ u,
    float* __restrict__ out) {
  __shared__ float s_uf[kRows2];
  __shared__ float s_scale[kT2];

  const int blk = blockIdx.x;
  const int b = blk / kChunks2;
  const int i0 = (blk % kChunks2) * kT2;
  const float* xb = x + (size_t)b * kL * kD;
  float* ob = out + (size_t)b * kL * kD;
  const double* ub = u + (size_t)b * kL;
  const int tid = threadIdx.x;

  // Wave 0: u -> fp32 for the dot. Wave 1: scale in fp64. Concurrent, one barrier.
  if (tid < kRows2) {
    const int row = i0 - kHalo + tid;
    s_uf[tid] = (row >= 0) ? (float)ub[row] : 0.0f;
  } else if (tid >= 64 && tid < 64 + kT2) {
    const int t = tid - 64;
    const int i = i0 + t;
    double wsum = 0.0;
#pragma unroll
    for (int k = 0; k < kW; ++k) {
      const int j = i - kHalo + k;
      if (j >= 0) wsum += ub[j];
    }
    const double uu = ub[i];
    s_scale[t] = (float)(uu / (uu * wsum + (double)kEps));
  }
  __syncthreads();

  // u -> registers (27 floats; all inner-loop indices static after unroll)
  float uf[kRows2];
#pragma unroll
  for (int r = 0; r < kRows2; ++r) uf[r] = s_uf[r];
  float sc[kT2];
#pragma unroll
  for (int t = 0; t < kT2; ++t) sc[t] = s_scale[t];

  const int c0 = 4 * tid;
  // 12-slot register ring, slot = local_row % 12, all indices compile-time.
  vfloat4 ring[kW];
#pragma unroll
  for (int r = 0; r < kHalo; ++r) {  // local rows 0..10 = global i0-11..i0-1
    const int row = i0 - kHalo + r;
    vfloat4 v = {0.f, 0.f, 0.f, 0.f};
    if (row >= 0) v = *(const vfloat4*)(xb + (size_t)row * kD + c0);
    ring[r] = v;
  }

#pragma unroll
  for (int t = 0; t < kT2; ++t) {
    const int i = i0 + t;
    const int r = kHalo + t;  // local row 11..26
    ring[r % kW] = *(const vfloat4*)(xb + (size_t)i * kD + c0);
    vfloat4 acc = {0.f, 0.f, 0.f, 0.f};
#pragma unroll
    for (int j = 0; j < kW; ++j) {
      const float uu = uf[r - j];
      const vfloat4 xv = ring[(r - j) % kW];
      acc.x += uu * xv.x; acc.y += uu * xv.y;
      acc.z += uu * xv.z; acc.w += uu * xv.w;
    }
    const float s = sc[t];
    vfloat4 o = {s * acc.x, s * acc.y, s * acc.z, s * acc.w};
    // output never re-read: don't pollute L2/L3 (keep x resident)
    __builtin_nontemporal_store(o, (vfloat4*)(ob + (size_t)i * kD + c0));
  }
}

extern "C" void kernel_launch(void* const* d_in, const int* in_sizes, int n_in,
                              void* d_out, int out_size, void* d_ws, size_t ws_size,
                              hipStream_t stream) {
  const float* x = (const float*)d_in[0];
  const float* Wa = (const float*)d_in[1];
  float* out = (float*)d_out;
  double* u = (double*)d_ws;  // 32768 * 8 B = 256 KB

  compute_u_kernel<<<kGridU, 256, 0, stream>>>(x, Wa, u);
  banded_v_kernel<<<kGridV, kThreads2, 0, stream>>>(x, u, out);
}